// Round 1
// baseline (328.583 us; speedup 1.0000x reference)
//
#include <hip/hip_runtime.h>

// SelfInteraction: out = norm( bilinear contractions of x0/x1 against 4 (128,128,128) weights )
// Strategy: 8 rank-1-coefficient GEMM channels (M=8192, K=16384, N=128) on f16 MFMA,
// weights pre-swizzled to fragment-stream order, fp32 accumulate, separate finalize.

#define C 128
#define NBATCH 8192

typedef _Float16 f16;
typedef _Float16 f16x8 __attribute__((ext_vector_type(8)));
typedef float f32x4 __attribute__((ext_vector_type(4)));

// ws layout:
// [0, 16MB)  : swizzled f16 weight streams, 4 weights x 2,097,152 f16 (order ss,vv,sv,vs)
//              stream index: ((((h*4+vb)*128+u)*4+wt)*64+lane)*8 + j
//              covering element W[u][ vb*32 + (lane>>4)*8 + j ][ h*64 + wt*16 + (lane&15) ]
// [16MB,32MB): raw channel sums f32 [8][8192][128]  (ss,vv,sv0..2,vs0..2)
#define WSTREAM_F16_PER_C (2*4*128*4*64*8)   // 2,097,152 f16 = 4MB
#define RAW_OFF_BYTES ((size_t)4*WSTREAM_F16_PER_C*2)  // 16 MB

__device__ __forceinline__ f16x8 splat8(f16 v) {
    return (f16x8){v, v, v, v, v, v, v, v};
}

union U16x8 { uint4 u; f16x8 h; };
__device__ __forceinline__ f16x8 as_h8(uint4 v) { U16x8 x; x.u = v; return x.h; }

__device__ __forceinline__ f32x4 mfma16(f16x8 a, f16x8 b, f32x4 c) {
    return __builtin_amdgcn_mfma_f32_16x16x32_f16(a, b, c, 0, 0, 0);
}

// ---------------- weight prep: fp32 -> f16, fragment-stream order ----------------
__global__ __launch_bounds__(256) void prep_weights(
        const float* __restrict__ Wss, const float* __restrict__ Wvv,
        const float* __restrict__ Wsv, const float* __restrict__ Wvs,
        f16* __restrict__ out) {
    __shared__ float lds[128 * 130];  // [v][w], stride 130 kills bank conflicts
    int c = blockIdx.x >> 7;
    int u = blockIdx.x & 127;
    const float* src = (c == 0 ? Wss : c == 1 ? Wvv : c == 2 ? Wsv : Wvs) + (size_t)u * 16384;
    for (int i = threadIdx.x; i < 16384; i += 256) {
        int v = i >> 7, w = i & 127;
        lds[v * 130 + w] = src[i];
    }
    __syncthreads();
    f16* dst = out + (size_t)c * WSTREAM_F16_PER_C;
    for (int pos = threadIdx.x; pos < 2048; pos += 256) {
        int h = pos >> 10, vb = (pos >> 8) & 3, wt = (pos >> 6) & 3, l = pos & 63;
        int v0 = vb * 32 + (l >> 4) * 8;
        int w = h * 64 + wt * 16 + (l & 15);
        f16x8 vals;
#pragma unroll
        for (int j = 0; j < 8; ++j) vals[j] = (f16)lds[(v0 + j) * 130 + w];
        size_t off = ((size_t)(((h * 4 + vb) * 128 + u) * 4 + wt) * 64 + l) * 8;
        *(f16x8*)(dst + off) = vals;
    }
}

// ---------------- main fused GEMM kernel ----------------
// grid = 256 blocks: blockIdx = zb*2 + h  (zb: 64-row z-tile, h: 64-col w-half)
// 512 threads = 8 waves; wave = channel: 0=ss 1=vv 2..4=sv_k 5..7=vs_k
__global__ __launch_bounds__(512, 2) void si_main(
        const float* __restrict__ x, const f16* __restrict__ wstream,
        float* __restrict__ raw) {
    __shared__ f16 x0T[128 * 64];       // [c][z]  (transposed)
    __shared__ f16 x1T[3 * 128 * 64];   // [k][v][z]

    int zb = blockIdx.x >> 1;
    int h = blockIdx.x & 1;
    int tid = threadIdx.x;

    // stage x tile (64 rows x 512 cols), transposed f16 into LDS
    for (int i = tid; i < 64 * 512; i += 512) {
        int z = i >> 9, col = i & 511;
        float v = x[(size_t)(zb * 64 + z) * 512 + col];
        f16 fv = (f16)v;
        if (col < 128) {
            x0T[col * 64 + z] = fv;
        } else {
            int cc = col - 128;
            int vv_ = cc / 3, k = cc - vv_ * 3;
            x1T[(k * 128 + vv_) * 64 + z] = fv;
        }
    }
    __syncthreads();

    int lane = tid & 63;
    int wv = tid >> 6;
    int l15 = lane & 15, lhi = lane >> 4;

    int cw = (wv == 0) ? 0 : (wv == 1) ? 1 : (wv < 5) ? 2 : 3;
    const f16* ps;  // scalar plane (indexed by u)
    const f16* pv;  // vector plane (indexed by v)
    if (wv == 0) { ps = x0T; pv = x0T; }
    else if (wv >= 2 && wv <= 4) { ps = x0T; pv = x1T + (wv - 2) * 128 * 64; }
    else { ps = x1T + (wv - 5) * 128 * 64; pv = x0T; }  // vs_k (unused for wv==1)

    const f16* wp = wstream + (size_t)cw * WSTREAM_F16_PER_C
                            + (size_t)h * (WSTREAM_F16_PER_C / 2);
    const uint4* bptr = (const uint4*)wp;  // per t-step: 256 uint4 (4 frags x 64 lanes)

    f32x4 acc[4][4];
#pragma unroll
    for (int s = 0; s < 4; ++s)
#pragma unroll
        for (int wt = 0; wt < 4; ++wt) acc[s][wt] = (f32x4){0.f, 0.f, 0.f, 0.f};

    uint4 bc[4], bn[4];
#pragma unroll
    for (int wt = 0; wt < 4; ++wt) bc[wt] = bptr[wt * 64 + lane];

    if (wv == 1) {
        // ---- vv channel: coeff[z,(u,v)] = sum_k x1k[z,u]*x1k[z,v] ----
        const f16* p0 = x1T;
        const f16* p1 = x1T + 128 * 64;
        const f16* p2 = x1T + 2 * 128 * 64;
        f16x8 vv0[4], vv1[4], vv2[4];
        for (int vb = 0; vb < 4; ++vb) {
#pragma unroll
            for (int s = 0; s < 4; ++s) {
                int zr = s * 16 + l15;
                f16x8 t0, t1, t2;
#pragma unroll
                for (int j = 0; j < 8; ++j) {
                    int vi = (vb * 32 + lhi * 8 + j) * 64 + zr;
                    t0[j] = p0[vi]; t1[j] = p1[vi]; t2[j] = p2[vi];
                }
                vv0[s] = t0; vv1[s] = t1; vv2[s] = t2;
            }
            for (int uu = 0; uu < 128; ++uu) {
                int t = vb * 128 + uu;
                const uint4* bnx = bptr + (size_t)(t + 1) * 256;
#pragma unroll
                for (int wt = 0; wt < 4; ++wt) bn[wt] = bnx[wt * 64 + lane];
                f16x8 A[4];
#pragma unroll
                for (int s = 0; s < 4; ++s) {
                    int zr = s * 16 + l15;
                    f16 a0 = p0[uu * 64 + zr];
                    f16 a1 = p1[uu * 64 + zr];
                    f16 a2 = p2[uu * 64 + zr];
                    A[s] = splat8(a0) * vv0[s] + splat8(a1) * vv1[s] + splat8(a2) * vv2[s];
                }
#pragma unroll
                for (int wt = 0; wt < 4; ++wt) {
                    f16x8 B = as_h8(bc[wt]);
#pragma unroll
                    for (int s = 0; s < 4; ++s) acc[s][wt] = mfma16(A[s], B, acc[s][wt]);
                }
#pragma unroll
                for (int wt = 0; wt < 4; ++wt) bc[wt] = bn[wt];
            }
        }
    } else {
        // ---- rank-1 channels: coeff[z,(u,v)] = ps[z,u] * pv[z,v] ----
        f16x8 vva[4];
        for (int vb = 0; vb < 4; ++vb) {
#pragma unroll
            for (int s = 0; s < 4; ++s) {
                int zr = s * 16 + l15;
                f16x8 tv;
#pragma unroll
                for (int j = 0; j < 8; ++j)
                    tv[j] = pv[(vb * 32 + lhi * 8 + j) * 64 + zr];
                vva[s] = tv;
            }
            for (int uu = 0; uu < 128; ++uu) {
                int t = vb * 128 + uu;
                const uint4* bnx = bptr + (size_t)(t + 1) * 256;
#pragma unroll
                for (int wt = 0; wt < 4; ++wt) bn[wt] = bnx[wt * 64 + lane];
                f16x8 A[4];
#pragma unroll
                for (int s = 0; s < 4; ++s) {
                    f16 sc = ps[uu * 64 + s * 16 + l15];
                    A[s] = splat8(sc) * vva[s];
                }
#pragma unroll
                for (int wt = 0; wt < 4; ++wt) {
                    f16x8 B = as_h8(bc[wt]);
#pragma unroll
                    for (int s = 0; s < 4; ++s) acc[s][wt] = mfma16(A[s], B, acc[s][wt]);
                }
#pragma unroll
                for (int wt = 0; wt < 4; ++wt) bc[wt] = bn[wt];
            }
        }
    }

    // write raw channel sums: raw[wv][z][w]
#pragma unroll
    for (int s = 0; s < 4; ++s)
#pragma unroll
        for (int wt = 0; wt < 4; ++wt)
#pragma unroll
            for (int i = 0; i < 4; ++i) {
                int z = zb * 64 + s * 16 + lhi * 4 + i;
                int w = h * 64 + wt * 16 + l15;
                raw[((size_t)wv * NBATCH + z) * 128 + w] = acc[s][wt][i];
            }
}

// ---------------- finalize: combine channels + normalizations ----------------
__global__ __launch_bounds__(64) void si_finalize(const float* __restrict__ raw,
                                                  float* __restrict__ out) {
    const float PW0 = 0.0055242717280199f;   // 1/sqrt(2*128*128); also == pw1*inv_sqrt3
    const float INV3 = 0.5773502691896258f;  // 1/sqrt(3)
    int z = blockIdx.x;
    int t = threadIdx.x;
    const size_t CS = (size_t)NBATCH * 128;
    const float* r0 = raw + (size_t)z * 128;

    // ---- scalar output y0 ----
    float ssA = r0[t], ssB = r0[t + 64];
    float vvA = r0[CS + t], vvB = r0[CS + t + 64];
    float y0A = PW0 * (ssA + INV3 * vvA);
    float y0B = PW0 * (ssB + INV3 * vvB);
    float s1 = y0A + y0B, s2 = y0A * y0A + y0B * y0B;
    for (int o = 32; o; o >>= 1) {
        s1 += __shfl_xor(s1, o);
        s2 += __shfl_xor(s2, o);
    }
    float mean = s1 * (1.0f / 128.0f);
    float var = (s2 - 128.0f * mean * mean) * (1.0f / 127.0f);
    float sc = 1.0f / (sqrtf(fmaxf(var, 0.0f)) + 1e-9f);
    out[(size_t)z * 512 + t] = y0A * sc;
    out[(size_t)z * 512 + t + 64] = y0B * sc;

    // ---- vector output yv ----
    float yA[3], yB[3];
    float nA = 1e-9f, nB = 1e-9f;
#pragma unroll
    for (int k = 0; k < 3; ++k) {
        float svA = r0[CS * (2 + k) + t], svB = r0[CS * (2 + k) + t + 64];
        float vsA = r0[CS * (5 + k) + t], vsB = r0[CS * (5 + k) + t + 64];
        yA[k] = PW0 * (svA + vsA);
        yB[k] = PW0 * (svB + vsB);
        nA += yA[k] * yA[k];
        nB += yB[k] * yB[k];
    }
    nA = sqrtf(nA);
    nB = sqrtf(nB);
    float t1 = nA + nB, t2 = nA * nA + nB * nB;
    for (int o = 32; o; o >>= 1) {
        t1 += __shfl_xor(t1, o);
        t2 += __shfl_xor(t2, o);
    }
    float meanv = t1 * (1.0f / 128.0f);
    float varv = (t2 - 128.0f * meanv * meanv) * (1.0f / 127.0f);
    float sv = 1.0f / (sqrtf(fmaxf(varv, 0.0f)) + 1e-9f);
#pragma unroll
    for (int k = 0; k < 3; ++k) {
        out[(size_t)z * 512 + 128 + t * 3 + k] = yA[k] * sv;
        out[(size_t)z * 512 + 128 + (t + 64) * 3 + k] = yB[k] * sv;
    }
}

extern "C" void kernel_launch(void* const* d_in, const int* in_sizes, int n_in,
                              void* d_out, int out_size, void* d_ws, size_t ws_size,
                              hipStream_t stream) {
    const float* x = (const float*)d_in[0];
    const float* Wss = (const float*)d_in[1];
    const float* Wvv = (const float*)d_in[2];
    const float* Wsv = (const float*)d_in[3];
    const float* Wvs = (const float*)d_in[4];
    f16* wstream = (f16*)d_ws;
    float* raw = (float*)((char*)d_ws + RAW_OFF_BYTES);  // needs ws_size >= 32MB
    float* out = (float*)d_out;

    hipLaunchKernelGGL(prep_weights, dim3(512), dim3(256), 0, stream,
                       Wss, Wvv, Wsv, Wvs, wstream);
    hipLaunchKernelGGL(si_main, dim3(256), dim3(512), 0, stream, x, wstream, raw);
    hipLaunchKernelGGL(si_finalize, dim3(NBATCH), dim3(64), 0, stream, raw, out);
}